// Round 6
// baseline (269.072 us; speedup 1.0000x reference)
//
#include <hip/hip_runtime.h>
#include <hip/hip_bf16.h>

typedef __bf16 bf16x8 __attribute__((ext_vector_type(8)));
typedef float f32x4 __attribute__((ext_vector_type(4)));
typedef unsigned short u16x8 __attribute__((ext_vector_type(8)));

#define B_    16
#define CIN   128
#define H_    112
#define W_    112
#define COUT  256
#define HO    54
#define WO    54
#define M_PER_B (HO*WO)        // 2916
#define HW    (H_*W_)          // 12544

__device__ __forceinline__ unsigned short f2bf(float v) {
    __hip_bfloat16 h = __float2bfloat16(v);
    return __builtin_bit_cast(unsigned short, h);
}

// ---------------------------------------------------------------------------
// K1: blocks 0..1791: S[b][h][w] = full 128-channel sum (byte-identical to r5).
//     Tail blocks: weight repack into fragment-ordered Wf.
// ---------------------------------------------------------------------------
__global__ __launch_bounds__(256) void sum_kernel(
    const float* __restrict__ in, const float* __restrict__ w,
    float* __restrict__ S, unsigned short* __restrict__ Wf)
{
    const int blk = blockIdx.x;
    const int tid = threadIdx.x;
    if (blk < B_ * H_) {
        __shared__ f32x4 red[8][28];
        const int b = blk / H_, h = blk % H_;
        if (tid < 224) {
            const int cg = tid / 28, ws = tid % 28;
            const float* p = in + ((size_t)(b * CIN + cg * 16) * H_ + h) * W_ + 4 * ws;
            f32x4 acc = (f32x4){0.f, 0.f, 0.f, 0.f};
            #pragma unroll
            for (int k = 0; k < 16; ++k)
                acc += *reinterpret_cast<const f32x4*>(p + (size_t)k * HW);
            red[cg][ws] = acc;
        }
        __syncthreads();
        if (tid < 28) {
            f32x4 s = red[0][tid];
            #pragma unroll
            for (int g = 1; g < 8; ++g) s += red[g][tid];
            *reinterpret_cast<f32x4*>(S + (size_t)(b * H_ + h) * W_ + 4 * tid) = s;
        }
    } else {
        int cid = (blk - B_ * H_) * 256 + tid;     // ((t*4+c0)*16+g)*64+L
        if (cid < 9 * 4 * 16 * 64) {
            int L   = cid & 63;
            int g   = (cid >> 6) & 15;
            int c0  = (cid >> 10) & 3;
            int t   = cid >> 12;
            int o   = g * 16 + (L & 15);
            int cb  = c0 * 32 + (L >> 4) * 8;
            u16x8 v;
            #pragma unroll
            for (int e = 0; e < 8; ++e)
                v[e] = f2bf(w[(size_t)(o * CIN + cb + e) * 9 + t]);
            *reinterpret_cast<u16x8*>(Wf + (size_t)cid * 8) = v;
        }
    }
}

// ---------------------------------------------------------------------------
// K2: T kernel (byte-identical to r5).
// ---------------------------------------------------------------------------
__global__ __launch_bounds__(128) void t_kernel(
    const float* __restrict__ S, float* __restrict__ T)
{
    __shared__ float Sr[5][112];
    const int blk = blockIdx.x;
    const int tid = threadIdx.x;
    const int b = blk / HO, y = blk % HO;
    for (int task = tid; task < 5 * 28; task += 128) {
        int row = task / 28, w4 = task % 28;
        *reinterpret_cast<f32x4*>(&Sr[row][4 * w4]) =
            *reinterpret_cast<const f32x4*>(S + (size_t)(b * H_ + 2 * y + row) * W_ + 4 * w4);
    }
    __syncthreads();
    if (tid < WO) {
        int x = tid;
        float s25 = 0.f, s9 = 0.f;
        #pragma unroll
        for (int i = 0; i < 5; ++i) {
            #pragma unroll
            for (int j = 0; j < 5; ++j) {
                float v = Sr[i][2 * x + j];
                s25 += v;
                if (!(i & 1) && !(j & 1)) s9 += v;
            }
        }
        T[(size_t)b * M_PER_B + y * WO + x] = 0.1f * (s25 - s9);
    }
}

// ---------------------------------------------------------------------------
// K3: conv — single delta vs r5: K split into two 64-channel passes over a
// half-size (21.5 KB) LDS patch -> 7 blocks/CU instead of 3 (28 waves/CU),
// no grid-tail quantization. Same swizzle, fragment mapping, epilogue.
// ---------------------------------------------------------------------------
#define STAGE_PASS(P)                                                          \
    {                                                                          \
        _Pragma("unroll")                                                      \
        for (int it = 0; it < 21; ++it) {                                      \
            int id = tid + it * 256;          /* < 5376 */                     \
            int ws = id % 28;                                                  \
            int cr = id / 28;                                                  \
            int r  = cr % 3;                                                   \
            int c  = cr / 3;                  /* 0..63 local channel */        \
            f32x4 v = *reinterpret_cast<const f32x4*>(                         \
                inb + ((size_t)((P) * 64 + c) * H_ + (2 * y + 2 * r)) * W_ + 4 * ws); \
            int p0 = r * 56 + 2 * ws;                                          \
            patch[p0 * 64 + (c ^ ((p0 & 7) << 3))] = f2bf(v[0]);               \
            int p1 = p0 + 1;                                                   \
            patch[p1 * 64 + (c ^ ((p1 & 7) << 3))] = f2bf(v[2]);               \
        }                                                                      \
    }

__global__ __launch_bounds__(256, 3) void conv_kernel(
    const float* __restrict__ in, const unsigned short* __restrict__ Wf,
    const float* __restrict__ T, const float* __restrict__ bias1,
    float* __restrict__ out)
{
    __shared__ unsigned short patch[168 * 64];       // 21,504 B

    const int tid = threadIdx.x;
    int bid = blockIdx.x;
    int wg  = (bid & 7) * 108 + (bid >> 3);          // XCD-contiguous (864%8==0)
    const int b = wg / HO;
    const int y = wg % HO;

    const float* inb = in + (size_t)b * CIN * HW;
    STAGE_PASS(0)
    __syncthreads();

    const int lane = tid & 63;
    const int wn   = tid >> 6;        // 0..3: n-group of 64 cols
    const int lm   = lane & 15;
    const int kq   = lane >> 4;

    int xm[4];
    #pragma unroll
    for (int mi = 0; mi < 4; ++mi) {
        int x = mi * 16 + lm;
        xm[mi] = (x > 53) ? 53 : x;
    }

    f32x4 acc[4][4];
    #pragma unroll
    for (int mi = 0; mi < 4; ++mi)
        #pragma unroll
        for (int ni = 0; ni < 4; ++ni)
            acc[mi][ni] = (f32x4){0.f, 0.f, 0.f, 0.f};

    const unsigned short* wfl = Wf + (size_t)(wn * 4) * 512 + lane * 8;

    bf16x8 bb[2][4];
    // preload s=0: (pass 0, t=0, c0local=0) -> slab 0
    #pragma unroll
    for (int ni = 0; ni < 4; ++ni)
        bb[0][ni] = __builtin_bit_cast(bf16x8,
            *reinterpret_cast<const u16x8*>(wfl + ni * 512));

    // step order: s = pass*18 + t*2 + c0local; Wf slab = t*4 + (2*pass + c0local)
    #pragma unroll
    for (int s = 0; s < 36; ++s) {
        const int cur = s & 1;
        if (s == 18) {
            __syncthreads();
            STAGE_PASS(1)
            __syncthreads();
        }
        if (s + 1 < 36) {
            const int sn = s + 1;
            const int pn = sn / 18, rn = sn % 18;
            const int slab_n = (rn >> 1) * 4 + 2 * pn + (rn & 1);
            const unsigned short* wnx = wfl + (size_t)slab_n * 16 * 512;
            #pragma unroll
            for (int ni = 0; ni < 4; ++ni)
                bb[cur ^ 1][ni] = __builtin_bit_cast(bf16x8,
                    *reinterpret_cast<const u16x8*>(wnx + ni * 512));
        }
        const int rr = s % 18;
        const int t  = rr >> 1;
        const int ki = t / 3, kj = t % 3;
        const int coff = (rr & 1) * 32 + kq * 8;
        bf16x8 a[4];
        #pragma unroll
        for (int mi = 0; mi < 4; ++mi) {
            int pos = ki * 56 + kj + xm[mi];
            int sa  = pos * 64 + (coff ^ ((pos & 7) << 3));
            a[mi] = __builtin_bit_cast(bf16x8,
                *reinterpret_cast<const u16x8*>(&patch[sa]));
        }
        #pragma unroll
        for (int mi = 0; mi < 4; ++mi)
            #pragma unroll
            for (int ni = 0; ni < 4; ++ni)
                acc[mi][ni] = __builtin_amdgcn_mfma_f32_16x16x32_bf16(
                    a[mi], bb[cur][ni], acc[mi][ni], 0, 0, 0);
    }

    // epilogue: out[b][o][y*54+x] = acc + bias1[o]*T[b][y*54+x]
    const float* Trow = T + (size_t)b * M_PER_B + y * WO;
    float* obase = out + (size_t)b * COUT * M_PER_B + y * WO;
    #pragma unroll
    for (int mi = 0; mi < 4; ++mi) {
        int mb = mi * 16 + kq * 4;
        if (mb >= WO) continue;
        bool full = (mb + 4 <= WO);
        float tv0 = Trow[mb], tv1 = Trow[mb + 1];
        float tv2 = 0.f, tv3 = 0.f;
        if (full) { tv2 = Trow[mb + 2]; tv3 = Trow[mb + 3]; }
        #pragma unroll
        for (int ni = 0; ni < 4; ++ni) {
            int o = wn * 64 + ni * 16 + lm;
            float bo = bias1[o];
            float* op = obase + (size_t)o * M_PER_B + mb;
            float2 r01 = make_float2(acc[mi][ni][0] + bo * tv0,
                                     acc[mi][ni][1] + bo * tv1);
            *reinterpret_cast<float2*>(op) = r01;
            if (full) {
                float2 r23 = make_float2(acc[mi][ni][2] + bo * tv2,
                                         acc[mi][ni][3] + bo * tv3);
                *reinterpret_cast<float2*>(op + 2) = r23;
            }
        }
    }
}

// ---------------------------------------------------------------------------
extern "C" void kernel_launch(void* const* d_in, const int* in_sizes, int n_in,
                              void* d_out, int out_size, void* d_ws, size_t ws_size,
                              hipStream_t stream)
{
    const float* in = (const float*)d_in[0];
    const float* w  = (const float*)d_in[1];
    const float* b1 = (const float*)d_in[2];
    float* out = (float*)d_out;

    char* ws = (char*)d_ws;
    float* S = (float*)ws;                                     // 802,816 B
    size_t off = 802816;
    float* T = (float*)(ws + off);  off += 186624;             // 16*2916*4
    unsigned short* Wf = (unsigned short*)(ws + off);          // 589,824 B

    sum_kernel<<<dim3(B_ * H_ + 144), 256, 0, stream>>>(in, w, S, Wf);
    t_kernel<<<dim3(B_ * HO), 128, 0, stream>>>(S, T);
    conv_kernel<<<dim3(HO * B_), 256, 0, stream>>>(in, Wf, T, b1, out);
}

// Round 7
// 225.790 us; speedup vs baseline: 1.1917x; 1.1917x over previous
//
#include <hip/hip_runtime.h>
#include <hip/hip_bf16.h>

typedef __bf16 bf16x8 __attribute__((ext_vector_type(8)));
typedef float f32x4 __attribute__((ext_vector_type(4)));
typedef unsigned short u16x8 __attribute__((ext_vector_type(8)));

#define B_    16
#define CIN   128
#define H_    112
#define W_    112
#define COUT  256
#define HO    54
#define WO    54
#define M_PER_B (HO*WO)        // 2916
#define HW    (H_*W_)          // 12544

__device__ __forceinline__ unsigned short f2bf(float v) {
    __hip_bfloat16 h = __float2bfloat16(v);
    return __builtin_bit_cast(unsigned short, h);
}

// ---------------------------------------------------------------------------
// K1: blocks 0..1791: S[b][h][w] = full 128-channel sum (byte-identical r5).
//     Tail blocks: weight repack into fragment-ordered Wf.
// ---------------------------------------------------------------------------
__global__ __launch_bounds__(256) void sum_kernel(
    const float* __restrict__ in, const float* __restrict__ w,
    float* __restrict__ S, unsigned short* __restrict__ Wf)
{
    const int blk = blockIdx.x;
    const int tid = threadIdx.x;
    if (blk < B_ * H_) {
        __shared__ f32x4 red[8][28];
        const int b = blk / H_, h = blk % H_;
        if (tid < 224) {
            const int cg = tid / 28, ws = tid % 28;
            const float* p = in + ((size_t)(b * CIN + cg * 16) * H_ + h) * W_ + 4 * ws;
            f32x4 acc = (f32x4){0.f, 0.f, 0.f, 0.f};
            #pragma unroll
            for (int k = 0; k < 16; ++k)
                acc += *reinterpret_cast<const f32x4*>(p + (size_t)k * HW);
            red[cg][ws] = acc;
        }
        __syncthreads();
        if (tid < 28) {
            f32x4 s = red[0][tid];
            #pragma unroll
            for (int g = 1; g < 8; ++g) s += red[g][tid];
            *reinterpret_cast<f32x4*>(S + (size_t)(b * H_ + h) * W_ + 4 * tid) = s;
        }
    } else {
        int cid = (blk - B_ * H_) * 256 + tid;     // ((t*4+c0)*16+g)*64+L
        if (cid < 9 * 4 * 16 * 64) {
            int L   = cid & 63;
            int g   = (cid >> 6) & 15;
            int c0  = (cid >> 10) & 3;
            int t   = cid >> 12;
            int o   = g * 16 + (L & 15);
            int cb  = c0 * 32 + (L >> 4) * 8;
            u16x8 v;
            #pragma unroll
            for (int e = 0; e < 8; ++e)
                v[e] = f2bf(w[(size_t)(o * CIN + cb + e) * 9 + t]);
            *reinterpret_cast<u16x8*>(Wf + (size_t)cid * 8) = v;
        }
    }
}

// ---------------------------------------------------------------------------
// K2: T kernel (byte-identical r5).
// ---------------------------------------------------------------------------
__global__ __launch_bounds__(128) void t_kernel(
    const float* __restrict__ S, float* __restrict__ T)
{
    __shared__ float Sr[5][112];
    const int blk = blockIdx.x;
    const int tid = threadIdx.x;
    const int b = blk / HO, y = blk % HO;
    for (int task = tid; task < 5 * 28; task += 128) {
        int row = task / 28, w4 = task % 28;
        *reinterpret_cast<f32x4*>(&Sr[row][4 * w4]) =
            *reinterpret_cast<const f32x4*>(S + (size_t)(b * H_ + 2 * y + row) * W_ + 4 * w4);
    }
    __syncthreads();
    if (tid < WO) {
        int x = tid;
        float s25 = 0.f, s9 = 0.f;
        #pragma unroll
        for (int i = 0; i < 5; ++i) {
            #pragma unroll
            for (int j = 0; j < 5; ++j) {
                float v = Sr[i][2 * x + j];
                s25 += v;
                if (!(i & 1) && !(j & 1)) s9 += v;
            }
        }
        T[(size_t)b * M_PER_B + y * WO + x] = 0.1f * (s25 - s9);
    }
}

// ---------------------------------------------------------------------------
// K3: conv — r3 structure (verified, 72 us). SINGLE DELTA: explicit 2-deep
// software pipeline for BOTH A (ds_read) and B (global) fragments: step s+1's
// 8 fragment loads are issued before step s's 16 MFMAs. All buffer indices
// compile-time (full unroll). Same LDS swizzle, fragment mapping, epilogue.
// ---------------------------------------------------------------------------
__global__ __launch_bounds__(256, 3) void conv_kernel(
    const float* __restrict__ in, const unsigned short* __restrict__ Wf,
    const float* __restrict__ T, const float* __restrict__ bias1,
    float* __restrict__ out)
{
    __shared__ unsigned short patch[168 * 128];      // 43,008 B

    const int tid = threadIdx.x;
    int bid = blockIdx.x;
    int wg  = (bid & 7) * 108 + (bid >> 3);          // XCD-contiguous (864%8==0)
    const int b = wg / HO;
    const int y = wg % HO;

    // stage: rows h = 2y, 2y+2, 2y+4; all 128 c; keep even w as bf16
    const float* inb = in + (size_t)b * CIN * HW;
    #pragma unroll
    for (int it = 0; it < 42; ++it) {
        int ch = tid + it * 256;          // ((c*3+r)*28+ws)
        int ws = ch % 28;
        int cr = ch / 28;
        int r  = cr % 3;
        int c  = cr / 3;
        f32x4 v = *reinterpret_cast<const f32x4*>(
            inb + ((size_t)c * H_ + (2 * y + 2 * r)) * W_ + 4 * ws);
        int p0 = r * 56 + 2 * ws;
        patch[p0 * 128 + (c ^ ((p0 & 7) << 3))] = f2bf(v[0]);
        int p1 = p0 + 1;
        patch[p1 * 128 + (c ^ ((p1 & 7) << 3))] = f2bf(v[2]);
    }
    __syncthreads();

    const int lane = tid & 63;
    const int wn   = tid >> 6;        // 0..3: n-group of 64 cols
    const int lm   = lane & 15;
    const int kq   = lane >> 4;
    const int koff = kq * 8;

    int xm[4];
    #pragma unroll
    for (int mi = 0; mi < 4; ++mi) {
        int x = mi * 16 + lm;
        xm[mi] = (x > 53) ? 53 : x;
    }

    f32x4 acc[4][4];
    #pragma unroll
    for (int mi = 0; mi < 4; ++mi)
        #pragma unroll
        for (int ni = 0; ni < 4; ++ni)
            acc[mi][ni] = (f32x4){0.f, 0.f, 0.f, 0.f};

    const unsigned short* wfl = Wf + (size_t)(wn * 4) * 512 + lane * 8;

    bf16x8 a[2][4], bb[2][4];

    // preload step 0
    #pragma unroll
    for (int ni = 0; ni < 4; ++ni)
        bb[0][ni] = __builtin_bit_cast(bf16x8,
            *reinterpret_cast<const u16x8*>(wfl + ni * 512));
    #pragma unroll
    for (int mi = 0; mi < 4; ++mi) {
        int pos = xm[mi];                              // t=0: ki=0,kj=0
        int sa  = pos * 128 + (koff ^ ((pos & 7) << 3));
        a[0][mi] = __builtin_bit_cast(bf16x8,
            *reinterpret_cast<const u16x8*>(&patch[sa]));
    }

    #pragma unroll
    for (int s = 0; s < 36; ++s) {
        const int cur = s & 1;
        if (s + 1 < 36) {
            const int sn = s + 1;
            // B fragments for step s+1 (global, L2-resident)
            const unsigned short* wnx = wfl + (size_t)sn * 16 * 512;
            #pragma unroll
            for (int ni = 0; ni < 4; ++ni)
                bb[cur ^ 1][ni] = __builtin_bit_cast(bf16x8,
                    *reinterpret_cast<const u16x8*>(wnx + ni * 512));
            // A fragments for step s+1 (LDS)
            const int tn  = sn >> 2, c0n = sn & 3;
            const int kin = tn / 3, kjn = tn % 3;
            #pragma unroll
            for (int mi = 0; mi < 4; ++mi) {
                int pos = kin * 56 + kjn + xm[mi];
                int sa  = pos * 128 + ((c0n * 32 + koff) ^ ((pos & 7) << 3));
                a[cur ^ 1][mi] = __builtin_bit_cast(bf16x8,
                    *reinterpret_cast<const u16x8*>(&patch[sa]));
            }
        }
        #pragma unroll
        for (int mi = 0; mi < 4; ++mi)
            #pragma unroll
            for (int ni = 0; ni < 4; ++ni)
                acc[mi][ni] = __builtin_amdgcn_mfma_f32_16x16x32_bf16(
                    a[cur][mi], bb[cur][ni], acc[mi][ni], 0, 0, 0);
    }

    // epilogue: out[b][o][y*54+x] = acc + bias1[o]*T[b][y*54+x]
    const float* Trow = T + (size_t)b * M_PER_B + y * WO;
    float* obase = out + (size_t)b * COUT * M_PER_B + y * WO;
    #pragma unroll
    for (int mi = 0; mi < 4; ++mi) {
        int mb = mi * 16 + kq * 4;
        if (mb >= WO) continue;
        bool full = (mb + 4 <= WO);
        float tv0 = Trow[mb], tv1 = Trow[mb + 1];
        float tv2 = 0.f, tv3 = 0.f;
        if (full) { tv2 = Trow[mb + 2]; tv3 = Trow[mb + 3]; }
        #pragma unroll
        for (int ni = 0; ni < 4; ++ni) {
            int o = wn * 64 + ni * 16 + lm;
            float bo = bias1[o];
            float* op = obase + (size_t)o * M_PER_B + mb;
            float2 r01 = make_float2(acc[mi][ni][0] + bo * tv0,
                                     acc[mi][ni][1] + bo * tv1);
            *reinterpret_cast<float2*>(op) = r01;
            if (full) {
                float2 r23 = make_float2(acc[mi][ni][2] + bo * tv2,
                                         acc[mi][ni][3] + bo * tv3);
                *reinterpret_cast<float2*>(op + 2) = r23;
            }
        }
    }
}

// ---------------------------------------------------------------------------
extern "C" void kernel_launch(void* const* d_in, const int* in_sizes, int n_in,
                              void* d_out, int out_size, void* d_ws, size_t ws_size,
                              hipStream_t stream)
{
    const float* in = (const float*)d_in[0];
    const float* w  = (const float*)d_in[1];
    const float* b1 = (const float*)d_in[2];
    float* out = (float*)d_out;

    char* ws = (char*)d_ws;
    float* S = (float*)ws;                                     // 802,816 B
    size_t off = 802816;
    float* T = (float*)(ws + off);  off += 186624;             // 16*2916*4
    unsigned short* Wf = (unsigned short*)(ws + off);          // 589,824 B

    sum_kernel<<<dim3(B_ * H_ + 144), 256, 0, stream>>>(in, w, S, Wf);
    t_kernel<<<dim3(B_ * HO), 128, 0, stream>>>(S, T);
    conv_kernel<<<dim3(HO * B_), 256, 0, stream>>>(in, Wf, T, b1, out);
}